// Round 1
// baseline (51679.883 us; speedup 1.0000x reference)
//
#include <hip/hip_runtime.h>

#define TT 512
#define BB 64
#define NI 512
#define NH 1024
#define NG 4096

using bf16x8 = __attribute__((ext_vector_type(8))) __bf16;
using f32x4  = __attribute__((ext_vector_type(4))) float;

static __device__ __forceinline__ unsigned short f2bf(float f) {
  unsigned int u = __float_as_uint(f);
  u += 0x7fffu + ((u >> 16) & 1u);
  return (unsigned short)(u >> 16);
}

// Permute gate rows to p = 4*col + gate (gate order i,f,g,o), convert to bf16,
// fold biases. orig row = gate*NH + col.
__global__ void prep_layer(const float* __restrict__ Wih, const float* __restrict__ Whh,
                           const float* __restrict__ bih, const float* __restrict__ bhh,
                           unsigned short* __restrict__ Wx, unsigned short* __restrict__ Wh,
                           float* __restrict__ bias, int Kx) {
  long nx = (long)NG * Kx;
  long nh = (long)NG * NH;
  long total = nx + nh + NG;
  for (long i = (long)blockIdx.x * blockDim.x + threadIdx.x; i < total;
       i += (long)gridDim.x * blockDim.x) {
    if (i < nx) {
      int p = (int)(i / Kx); int k = (int)(i - (long)p * Kx);
      int orig = (p & 3) * NH + (p >> 2);
      Wx[i] = f2bf(Wih[(long)orig * Kx + k]);
    } else if (i < nx + nh) {
      long j = i - nx;
      int p = (int)(j / NH); int k = (int)(j - (long)p * NH);
      int orig = (p & 3) * NH + (p >> 2);
      Wh[j] = f2bf(Whh[(long)orig * NH + k]);
    } else {
      int p = (int)(i - nx - nh);
      int orig = (p & 3) * NH + (p >> 2);
      bias[p] = bih[orig] + bhh[orig];
    }
  }
}

// emb_f[t*BB+b][:] = enc[tok[b][t]]; emb_r uses reversed-within-length index.
__global__ void prep_emb(const int* __restrict__ tok, const int* __restrict__ lens,
                         const float* __restrict__ enc,
                         unsigned short* __restrict__ embf, unsigned short* __restrict__ embr) {
  int row = blockIdx.x;            // t*BB + b
  int t = row / BB, b = row - (row / BB) * BB;
  int L = lens[b];
  int tf = tok[b * TT + t];
  int ir = (t < L) ? (L - 1 - t) : t;
  int tr_ = tok[b * TT + ir];
  int i = threadIdx.x;             // 0..127 -> 4 floats each
  float4 vf = *(const float4*)(enc + (long)tf * NI + i * 4);
  float4 vr = *(const float4*)(enc + (long)tr_ * NI + i * 4);
  ushort4 of = make_ushort4(f2bf(vf.x), f2bf(vf.y), f2bf(vf.z), f2bf(vf.w));
  ushort4 orr = make_ushort4(f2bf(vr.x), f2bf(vr.y), f2bf(vr.z), f2bf(vr.w));
  *(ushort4*)(embf + (long)row * NI + i * 4) = of;
  *(ushort4*)(embr + (long)row * NI + i * 4) = orr;
}

struct KP {
  const int* lens;
  const unsigned short* emb[2];    // [dir] (T*B, NI) bf16
  unsigned short* h0all[2];        // [dir] (T*B, NH) bf16  (layer-0 masked outputs)
  const unsigned short* Wx[4];     // [dir*2+layer] (NG, Kx) bf16, permuted rows
  const unsigned short* Wh[4];     // (NG, NH) bf16, permuted rows
  const float* bias[4];            // (NG) f32, permuted rows
  unsigned short* hbuf[4];         // (2, BB, NH) bf16 ping-pong carry-h
  unsigned int* cnt;               // 2 group counters, 128B apart
  float* out;                      // (T, B, 2048) f32
};

template <int KS>
static __device__ __forceinline__ void load_w(bf16x8* w, const unsigned short* Wsrc,
                                              int rowg, int Ksrc) {
  int lane = threadIdx.x & 63;
  const unsigned short* p = Wsrc + (long)(rowg + (lane & 15)) * Ksrc + (lane >> 4) * 8;
#pragma unroll
  for (int ks = 0; ks < KS; ++ks) w[ks] = *(const bf16x8*)(p + ks * 32);
}

// acc[nt] += W(16 rows owned by this wave) x B(batch tile nt), K = KS*32.
template <int KS>
static __device__ __forceinline__ void do_mfma(const bf16x8* w, f32x4* acc,
                                               const unsigned short* src, int row0, int stride) {
  int lane = threadIdx.x & 63;
  int ln = lane & 15, kg = lane >> 4;
  const unsigned short* p0 = src + (long)(row0 + ln) * stride + kg * 8;
  long rs = (long)stride * 16;
  bf16x8 b0[4], b1[4];
#pragma unroll
  for (int nt = 0; nt < 4; ++nt) b0[nt] = *(const bf16x8*)(p0 + nt * rs);
#pragma unroll
  for (int ks = 0; ks < KS; ++ks) {
    if (ks + 1 < KS) {
#pragma unroll
      for (int nt = 0; nt < 4; ++nt) {
        bf16x8 v = *(const bf16x8*)(p0 + nt * rs + (ks + 1) * 32);
        if (ks & 1) b0[nt] = v; else b1[nt] = v;
      }
    }
#pragma unroll
    for (int nt = 0; nt < 4; ++nt) {
      bf16x8 cur = (ks & 1) ? b1[nt] : b0[nt];
      acc[nt] = __builtin_amdgcn_mfma_f32_16x16x32_bf16(w[ks], cur, acc[nt], 0, 0, 0);
    }
  }
}

// 128 wgs: wg 0..63 forward chain (f0 then f1), 64..127 reverse chain.
// wg owns 64 permuted gate rows = 16 h-columns. 8 waves: mt = wave&3 (16-row tile),
// kap = wave>>2 (0: x-part weights, 1: h-part weights). Partials combined via LDS.
__global__ void __launch_bounds__(512, 2) lstm_main(KP P) {
  __shared__ f32x4 red[4 * 4 * 64];   // 16 KB
  const int tid = threadIdx.x;
  const int lane = tid & 63;
  const int wave = tid >> 6;
  const int mt = wave & 3, kap = wave >> 2;
  const int wg = blockIdx.x;
  const int dir = wg >> 6, wl = wg & 63;
  const int row0 = wl * 64;
  const int ln = lane & 15, kg = lane >> 4;
  unsigned int* cnt = P.cnt + dir * 32;

  int lens_v[4];
#pragma unroll
  for (int nt = 0; nt < 4; ++nt) lens_v[nt] = P.lens[nt * 16 + ln];
  const int mycol = wl * 16 + mt * 4 + kg;   // h-column of this lane's 4 acc regs

  for (int layer = 0; layer < 2; ++layer) {
    const int li = dir * 2 + layer;
    bf16x8 w[32];
    if (kap == 0) {
      if (layer == 0) load_w<16>(w, P.Wx[li], row0 + mt * 16, NI);
      else            load_w<32>(w, P.Wx[li], row0 + mt * 16, NH);
    } else {
      load_w<32>(w, P.Wh[li], row0 + mt * 16, NH);
    }
    f32x4 bias_v;
    {
      const float* bp = P.bias[li] + row0 + mt * 16 + kg * 4;
      bias_v[0] = bp[0]; bias_v[1] = bp[1]; bias_v[2] = bp[2]; bias_v[3] = bp[3];
    }
    float c_s[4] = {0.f, 0.f, 0.f, 0.f};
    float h_s[4] = {0.f, 0.f, 0.f, 0.f};
    unsigned short* hb = P.hbuf[li];
    const unsigned short* xsrc =
        (layer == 0) ? P.emb[dir] : (const unsigned short*)P.h0all[dir];

    for (int t = 0; t < TT; ++t) {
      f32x4 acc[4];
#pragma unroll
      for (int nt = 0; nt < 4; ++nt) {
        if (kap == 0) acc[nt] = bias_v;
        else { f32x4 z = {0.f, 0.f, 0.f, 0.f}; acc[nt] = z; }
      }
      if (kap == 0) {
        if (layer == 0) do_mfma<16>(w, acc, xsrc, t * BB, NI);
        else            do_mfma<32>(w, acc, xsrc, t * BB, NH);
      } else if (t > 0) {
        do_mfma<32>(w, acc, hb + ((t - 1) & 1) * (BB * NH), 0, NH);
      }
      if (kap == 1) {
#pragma unroll
        for (int nt = 0; nt < 4; ++nt) red[(mt * 4 + nt) * 64 + lane] = acc[nt];
      }
      __syncthreads();
      if (kap == 0) {
#pragma unroll
        for (int nt = 0; nt < 4; ++nt) {
          f32x4 r = red[(mt * 4 + nt) * 64 + lane];
          float gi = acc[nt][0] + r[0];
          float gf = acc[nt][1] + r[1];
          float gg = acc[nt][2] + r[2];
          float go = acc[nt][3] + r[3];
          float iv = 1.f / (1.f + __expf(-gi));
          float fv = 1.f / (1.f + __expf(-gf));
          float gv = tanhf(gg);
          float ov = 1.f / (1.f + __expf(-go));
          float cn = fv * c_s[nt] + iv * gv;
          float hn = ov * tanhf(cn);
          bool m = (t < lens_v[nt]);
          c_s[nt] = m ? cn : c_s[nt];
          float hc = m ? hn : h_s[nt];
          h_s[nt] = hc;
          int b = nt * 16 + ln;
          hb[(t & 1) * (BB * NH) + b * NH + mycol] = f2bf(hc);
          float outv = m ? hn : 0.f;
          if (layer == 0)
            P.h0all[dir][(long)(t * BB + b) * NH + mycol] = f2bf(outv);
          else
            P.out[(long)(t * BB + b) * 2048 + dir * NH + mycol] = outv;
        }
      }
      __threadfence();
      __syncthreads();
      if (tid == 0) {
        __hip_atomic_fetch_add(cnt, 1u, __ATOMIC_RELEASE, __HIP_MEMORY_SCOPE_AGENT);
        unsigned int target = (unsigned int)(layer * TT + t + 1) * 64u;
        while (__hip_atomic_load(cnt, __ATOMIC_RELAXED, __HIP_MEMORY_SCOPE_AGENT) < target) {
          __builtin_amdgcn_s_sleep(2);
        }
        __threadfence();
      }
      __syncthreads();
    }
  }
}

extern "C" void kernel_launch(void* const* d_in, const int* in_sizes, int n_in,
                              void* d_out, int out_size, void* d_ws, size_t ws_size,
                              hipStream_t stream) {
  (void)in_sizes; (void)n_in; (void)out_size; (void)ws_size;
  const int* input = (const int*)d_in[0];
  const int* lens  = (const int*)d_in[1];
  const float* enc = (const float*)d_in[2];
  // li = dir*2+layer: 0=f0(3..6) 1=f1(7..10) 2=r0(11..14) 3=r1(15..18)
  const float* Wih[4] = {(const float*)d_in[3],  (const float*)d_in[7],
                         (const float*)d_in[11], (const float*)d_in[15]};
  const float* Whh[4] = {(const float*)d_in[4],  (const float*)d_in[8],
                         (const float*)d_in[12], (const float*)d_in[16]};
  const float* bih[4] = {(const float*)d_in[5],  (const float*)d_in[9],
                         (const float*)d_in[13], (const float*)d_in[17]};
  const float* bhh[4] = {(const float*)d_in[6],  (const float*)d_in[10],
                         (const float*)d_in[14], (const float*)d_in[18]};

  char* ws = (char*)d_ws;
  size_t off = 0;
  auto carve = [&](size_t bytes) -> char* {
    char* p = ws + off;
    off += (bytes + 255) & ~(size_t)255;
    return p;
  };
  unsigned short* emb[2];
  emb[0] = (unsigned short*)carve((size_t)TT * BB * NI * 2);
  emb[1] = (unsigned short*)carve((size_t)TT * BB * NI * 2);
  unsigned short* h0a[2];
  h0a[0] = (unsigned short*)carve((size_t)TT * BB * NH * 2);
  h0a[1] = (unsigned short*)carve((size_t)TT * BB * NH * 2);
  unsigned short* Wx[4]; unsigned short* Wh[4]; float* bias[4]; unsigned short* hbuf[4];
  for (int li = 0; li < 4; ++li) {
    int Kx = (li & 1) ? NH : NI;
    Wx[li]   = (unsigned short*)carve((size_t)NG * Kx * 2);
    Wh[li]   = (unsigned short*)carve((size_t)NG * NH * 2);
    bias[li] = (float*)carve((size_t)NG * 4);
    hbuf[li] = (unsigned short*)carve((size_t)2 * BB * NH * 2);
  }
  unsigned int* cnt = (unsigned int*)carve(256);

  hipMemsetAsync(cnt, 0, 256, stream);
  for (int li = 0; li < 4; ++li) {
    int Kx = (li & 1) ? NH : NI;
    prep_layer<<<2048, 256, 0, stream>>>(Wih[li], Whh[li], bih[li], bhh[li],
                                         Wx[li], Wh[li], bias[li], Kx);
  }
  prep_emb<<<TT * BB, 128, 0, stream>>>(input, lens, enc, emb[0], emb[1]);

  KP p;
  p.lens = lens;
  p.emb[0] = emb[0]; p.emb[1] = emb[1];
  p.h0all[0] = h0a[0]; p.h0all[1] = h0a[1];
  for (int li = 0; li < 4; ++li) {
    p.Wx[li] = Wx[li]; p.Wh[li] = Wh[li]; p.bias[li] = bias[li]; p.hbuf[li] = hbuf[li];
  }
  p.cnt = cnt;
  p.out = (float*)d_out;

  void* args[] = {&p};
  hipLaunchCooperativeKernel(lstm_main, dim3(128), dim3(512), args, 0, stream);
}

// Round 2
// 13485.956 us; speedup vs baseline: 3.8321x; 3.8321x over previous
//
#include <hip/hip_runtime.h>

#define TT 512
#define BB 64
#define NI 512
#define NH 1024
#define NG 4096

using bf16x8 = __attribute__((ext_vector_type(8))) __bf16;
using f32x4  = __attribute__((ext_vector_type(4))) float;

static __device__ __forceinline__ unsigned short f2bf(float f) {
  unsigned int u = __float_as_uint(f);
  u += 0x7fffu + ((u >> 16) & 1u);
  return (unsigned short)(u >> 16);
}

// ---------------- prep kernels (unchanged from round 0, proven) ----------------
// Permute gate rows to p = 4*col + gate (gate order i,f,g,o), convert to bf16,
// fold biases. orig row = gate*NH + col.
__global__ void prep_layer(const float* __restrict__ Wih, const float* __restrict__ Whh,
                           const float* __restrict__ bih, const float* __restrict__ bhh,
                           unsigned short* __restrict__ Wx, unsigned short* __restrict__ Wh,
                           float* __restrict__ bias, int Kx) {
  long nx = (long)NG * Kx;
  long nh = (long)NG * NH;
  long total = nx + nh + NG;
  for (long i = (long)blockIdx.x * blockDim.x + threadIdx.x; i < total;
       i += (long)gridDim.x * blockDim.x) {
    if (i < nx) {
      int p = (int)(i / Kx); int k = (int)(i - (long)p * Kx);
      int orig = (p & 3) * NH + (p >> 2);
      Wx[i] = f2bf(Wih[(long)orig * Kx + k]);
    } else if (i < nx + nh) {
      long j = i - nx;
      int p = (int)(j / NH); int k = (int)(j - (long)p * NH);
      int orig = (p & 3) * NH + (p >> 2);
      Wh[j] = f2bf(Whh[(long)orig * NH + k]);
    } else {
      int p = (int)(i - nx - nh);
      int orig = (p & 3) * NH + (p >> 2);
      bias[p] = bih[orig] + bhh[orig];
    }
  }
}

__global__ void prep_emb(const int* __restrict__ tok, const int* __restrict__ lens,
                         const float* __restrict__ enc,
                         unsigned short* __restrict__ embf, unsigned short* __restrict__ embr) {
  int row = blockIdx.x;            // t*BB + b
  int t = row / BB, b = row - (row / BB) * BB;
  int L = lens[b];
  int tf = tok[b * TT + t];
  int ir = (t < L) ? (L - 1 - t) : t;
  int tr_ = tok[b * TT + ir];
  int i = threadIdx.x;             // 0..127 -> 4 floats each
  float4 vf = *(const float4*)(enc + (long)tf * NI + i * 4);
  float4 vr = *(const float4*)(enc + (long)tr_ * NI + i * 4);
  ushort4 of = make_ushort4(f2bf(vf.x), f2bf(vf.y), f2bf(vf.z), f2bf(vf.w));
  ushort4 orr = make_ushort4(f2bf(vr.x), f2bf(vr.y), f2bf(vr.z), f2bf(vr.w));
  *(ushort4*)(embf + (long)row * NI + i * 4) = of;
  *(ushort4*)(embr + (long)row * NI + i * 4) = orr;
}

// ---------------- main persistent kernel ----------------
struct KP {
  const int* lens;
  const unsigned short* emb[2];    // [dir] (T*B, NI) bf16
  unsigned short* h0all[2];        // [dir] (T*B, NH) bf16 (layer-0 masked outputs)
  const unsigned short* Wx[4];     // [g] (NG, Kx) bf16, permuted rows
  const unsigned short* Wh[4];     // [g] (NG, NH) bf16, permuted rows
  const float* bias[4];            // [g] (NG) f32, permuted rows
  unsigned short* hbuf[4];         // [g] (2, BB, NH) bf16 ping-pong carry-h
  unsigned int* slots;             // 4 groups x 64 slots
  float* out;                      // (T, B, 2048) f32
};

// agent-scope (sc1) relaxed stores: write through to coherent L3
static __device__ __forceinline__ void ast4(unsigned short* p, unsigned v) {
  __hip_atomic_store((unsigned*)p, v, __ATOMIC_RELAXED, __HIP_MEMORY_SCOPE_AGENT);
}
static __device__ __forceinline__ void ast8(float* p, unsigned long long v) {
  __hip_atomic_store((unsigned long long*)p, v, __ATOMIC_RELAXED, __HIP_MEMORY_SCOPE_AGENT);
}

// wave-parallel poll of 64 slots; acquire fence (buffer_inv) on success so the
// following PLAIN loads re-fetch fresh data from L3.
static __device__ __forceinline__ void poll64(const unsigned int* slots, unsigned tgt) {
  int lane = threadIdx.x & 63;
  for (;;) {
    unsigned v = __hip_atomic_load(slots + lane, __ATOMIC_RELAXED, __HIP_MEMORY_SCOPE_AGENT);
    if (__all((int)(v >= tgt))) break;
    __builtin_amdgcn_s_sleep(2);
  }
  __builtin_amdgcn_fence(__ATOMIC_ACQUIRE, "agent");
}

// wave owns 64 gate rows x a K-quarter. w[mt*KQ+ks].
template <int KQ>
static __device__ __forceinline__ void loadw_q(bf16x8* w, const unsigned short* Wsrc,
                                               int row0, int kbase, int Kfull,
                                               int ln, int kg) {
#pragma unroll
  for (int mt = 0; mt < 4; ++mt) {
    const unsigned short* p = Wsrc + (long)(row0 + mt * 16 + ln) * Kfull + kbase + kg * 8;
#pragma unroll
    for (int ks = 0; ks < KQ; ++ks) w[mt * KQ + ks] = *(const bf16x8*)(p + ks * 32);
  }
}

template <int KQ>
static __device__ __forceinline__ void gemm_q(const bf16x8* w, f32x4* acc,
                                              const unsigned short* src, int stride,
                                              int kbase, int ln, int kg) {
  const unsigned short* p0 = src + (long)ln * stride + kbase + kg * 8;
  const long rs = (long)stride * 16;
  bf16x8 bA[4], bB[4];
#pragma unroll
  for (int nt = 0; nt < 4; ++nt) bA[nt] = *(const bf16x8*)(p0 + nt * rs);
  if (KQ > 1) {
#pragma unroll
    for (int nt = 0; nt < 4; ++nt) bB[nt] = *(const bf16x8*)(p0 + nt * rs + 32);
  }
#pragma unroll
  for (int ks = 0; ks < KQ; ++ks) {
#pragma unroll
    for (int mt = 0; mt < 4; ++mt)
#pragma unroll
      for (int nt = 0; nt < 4; ++nt)
        acc[mt * 4 + nt] = __builtin_amdgcn_mfma_f32_16x16x32_bf16(
            w[mt * KQ + ks], (ks & 1) ? bB[nt] : bA[nt], acc[mt * 4 + nt], 0, 0, 0);
    if (ks + 2 < KQ) {
#pragma unroll
      for (int nt = 0; nt < 4; ++nt) {
        bf16x8 v = *(const bf16x8*)(p0 + nt * rs + (ks + 2) * 32);
        if (ks & 1) bB[nt] = v; else bA[nt] = v;
      }
    }
  }
}

// 256 wgs x 512 thr. group g = wg>>6: 0=f0 1=f1 2=r0 3=r1 (dir=g>>1, layer=g&1).
// wg owns 64 permuted gate rows (16 h-columns). wave = part(x|h)*4 + q(K-quarter).
__global__ void __launch_bounds__(512, 2) lstm_main(KP P) {
  __shared__ f32x4 red[8 * 16 * 64];   // 128 KB: 8 waves x 16 (mt,nt) x 64 lanes
  const int tid = threadIdx.x, lane = tid & 63, wave = tid >> 6;
  const int part = wave >> 2;          // 0: x-part, 1: h-part
  const int q = wave & 3;              // K-quarter
  const int wg = blockIdx.x, g = wg >> 6, wl = wg & 63;
  const int dir = g >> 1, layer = g & 1;
  const int ln = lane & 15, kg = lane >> 4;
  unsigned int* own = P.slots + g * 64;
  unsigned int* prv = P.slots + (layer ? (g - 1) * 64 : 0);

  // epilogue ownership: thread -> (batch eb, cols ec, ec+1)
  const int eb = tid >> 3;
  const int ec = (tid & 7) * 2;
  const int colg = wl * 16 + ec;
  const int L = P.lens[eb];
  float cst[2] = {0.f, 0.f};
  float hst[2] = {0.f, 0.f};

  // weights: registers, loaded once
  bf16x8 w[32];
  const int row0 = wl * 64;
  if (part == 0) {
    if (layer) loadw_q<8>(w, P.Wx[g], row0, q * 256, NH, ln, kg);
    else       loadw_q<4>(w, P.Wx[g], row0, q * 128, NI, ln, kg);
  } else {
    loadw_q<8>(w, P.Wh[g], row0, q * 256, NH, ln, kg);
  }
  unsigned short* hb = P.hbuf[g];
  const unsigned short* xsrc = layer ? (const unsigned short*)P.h0all[dir] : P.emb[dir];

  for (int t = 0; t < TT; ++t) {
    f32x4 acc[16];
    if (wave == 0) {   // wave 0 seeds bias so epilogue is a pure sum
#pragma unroll
      for (int mt = 0; mt < 4; ++mt) {
        f32x4 bv = *(const f32x4*)(P.bias[g] + (wl * 16 + mt * 4 + kg) * 4);
#pragma unroll
        for (int nt = 0; nt < 4; ++nt) acc[mt * 4 + nt] = bv;
      }
    } else {
#pragma unroll
      for (int i = 0; i < 16; ++i) { f32x4 z = {0.f, 0.f, 0.f, 0.f}; acc[i] = z; }
    }

    if (part == 1) {
      if (t > 0) {
        poll64(own, (unsigned)t);                      // all wgs finished tick t-1
        gemm_q<8>(w, acc, hb + ((t - 1) & 1) * (BB * NH), NH, q * 256, ln, kg);
      }
    } else if (layer) {
      poll64(prv, (unsigned)(t + 1));                  // layer-0 finished tick t
      gemm_q<8>(w, acc, xsrc + (long)t * BB * NH, NH, q * 256, ln, kg);
    } else {
      gemm_q<4>(w, acc, xsrc + (long)t * BB * NI, NI, q * 128, ln, kg);
    }

#pragma unroll
    for (int i = 0; i < 16; ++i) red[(wave * 16 + i) * 64 + lane] = acc[i];
    __syncthreads();

    // epilogue: every thread finishes 2 (batch,col) units
    float hv[2], ov2[2];
#pragma unroll
    for (int u = 0; u < 2; ++u) {
      const int c = ec + u;
      const int mt = c >> 2, kk = c & 3;
      const int nt = eb >> 4;
      const int l2 = (kk << 4) | (eb & 15);
      f32x4 gs = {0.f, 0.f, 0.f, 0.f};
#pragma unroll
      for (int w2 = 0; w2 < 8; ++w2) gs += red[(w2 * 16 + mt * 4 + nt) * 64 + l2];
      float iv = 1.f / (1.f + __expf(-gs[0]));
      float fv = 1.f / (1.f + __expf(-gs[1]));
      float gv = 1.f - 2.f / (1.f + __expf(2.f * gs[2]));
      float og = 1.f / (1.f + __expf(-gs[3]));
      float cn = fv * cst[u] + iv * gv;
      float tc = 1.f - 2.f / (1.f + __expf(2.f * cn));
      float hn = og * tc;
      bool m = t < L;
      cst[u] = m ? cn : cst[u];
      float hk = m ? hn : hst[u];
      hst[u] = hk;
      hv[u] = hk;
      ov2[u] = m ? hn : 0.f;
    }
    unsigned hp = (unsigned)f2bf(hv[0]) | ((unsigned)f2bf(hv[1]) << 16);
    ast4(hb + (t & 1) * (BB * NH) + eb * NH + colg, hp);
    if (layer == 0) {
      unsigned op = (unsigned)f2bf(ov2[0]) | ((unsigned)f2bf(ov2[1]) << 16);
      ast4(P.h0all[dir] + (long)(t * BB + eb) * NH + colg, op);
    } else {
      union { float f[2]; unsigned long long q; } U;
      U.f[0] = ov2[0]; U.f[1] = ov2[1];
      ast8(P.out + (long)(t * BB + eb) * 2048 + dir * NH + colg, U.q);
    }

    __syncthreads();   // drains all waves' sc1 stores (vmcnt0 before s_barrier)
    if (tid == 0)
      __hip_atomic_store(own + wl, (unsigned)(t + 1), __ATOMIC_RELEASE,
                         __HIP_MEMORY_SCOPE_AGENT);
  }
}

extern "C" void kernel_launch(void* const* d_in, const int* in_sizes, int n_in,
                              void* d_out, int out_size, void* d_ws, size_t ws_size,
                              hipStream_t stream) {
  (void)in_sizes; (void)n_in; (void)out_size; (void)ws_size;
  const int* input = (const int*)d_in[0];
  const int* lens  = (const int*)d_in[1];
  const float* enc = (const float*)d_in[2];
  // g = dir*2+layer: 0=f0(3..6) 1=f1(7..10) 2=r0(11..14) 3=r1(15..18)
  const float* Wih[4] = {(const float*)d_in[3],  (const float*)d_in[7],
                         (const float*)d_in[11], (const float*)d_in[15]};
  const float* Whh[4] = {(const float*)d_in[4],  (const float*)d_in[8],
                         (const float*)d_in[12], (const float*)d_in[16]};
  const float* bih[4] = {(const float*)d_in[5],  (const float*)d_in[9],
                         (const float*)d_in[13], (const float*)d_in[17]};
  const float* bhh[4] = {(const float*)d_in[6],  (const float*)d_in[10],
                         (const float*)d_in[14], (const float*)d_in[18]};

  char* ws = (char*)d_ws;
  size_t off = 0;
  auto carve = [&](size_t bytes) -> char* {
    char* p = ws + off;
    off += (bytes + 255) & ~(size_t)255;
    return p;
  };
  unsigned short* emb[2];
  emb[0] = (unsigned short*)carve((size_t)TT * BB * NI * 2);
  emb[1] = (unsigned short*)carve((size_t)TT * BB * NI * 2);
  unsigned short* h0a[2];
  h0a[0] = (unsigned short*)carve((size_t)TT * BB * NH * 2);
  h0a[1] = (unsigned short*)carve((size_t)TT * BB * NH * 2);
  unsigned short* Wx[4]; unsigned short* Wh[4]; float* bias[4]; unsigned short* hbuf[4];
  for (int li = 0; li < 4; ++li) {
    int Kx = (li & 1) ? NH : NI;
    Wx[li]   = (unsigned short*)carve((size_t)NG * Kx * 2);
    Wh[li]   = (unsigned short*)carve((size_t)NG * NH * 2);
    bias[li] = (float*)carve((size_t)NG * 4);
    hbuf[li] = (unsigned short*)carve((size_t)2 * BB * NH * 2);
  }
  unsigned int* slots = (unsigned int*)carve(1024);

  hipMemsetAsync(slots, 0, 1024, stream);
  for (int li = 0; li < 4; ++li) {
    int Kx = (li & 1) ? NH : NI;
    prep_layer<<<2048, 256, 0, stream>>>(Wih[li], Whh[li], bih[li], bhh[li],
                                         Wx[li], Wh[li], bias[li], Kx);
  }
  prep_emb<<<TT * BB, 128, 0, stream>>>(input, lens, enc, emb[0], emb[1]);

  KP p;
  p.lens = lens;
  p.emb[0] = emb[0]; p.emb[1] = emb[1];
  p.h0all[0] = h0a[0]; p.h0all[1] = h0a[1];
  for (int li = 0; li < 4; ++li) {
    p.Wx[li] = Wx[li]; p.Wh[li] = Wh[li]; p.bias[li] = bias[li]; p.hbuf[li] = hbuf[li];
  }
  p.slots = slots;
  p.out = (float*)d_out;

  void* args[] = {&p};
  hipLaunchCooperativeKernel(lstm_main, dim3(256), dim3(512), args, 0, stream);
}

// Round 3
// 6940.108 us; speedup vs baseline: 7.4466x; 1.9432x over previous
//
#include <hip/hip_runtime.h>

#define TT 512
#define BB 64
#define NI 512
#define NH 1024
#define NG 4096

using bf16x8 = __attribute__((ext_vector_type(8))) __bf16;
using f32x4  = __attribute__((ext_vector_type(4))) float;

static __device__ __forceinline__ unsigned short f2bf(float f) {
  unsigned int u = __float_as_uint(f);
  u += 0x7fffu + ((u >> 16) & 1u);
  return (unsigned short)(u >> 16);
}

// ---------------- prep kernels (proven rounds 0-2) ----------------
// Permute gate rows to p = 4*col + gate (gate order i,f,g,o), convert to bf16,
// fold biases. orig row = gate*NH + col.
__global__ void prep_layer(const float* __restrict__ Wih, const float* __restrict__ Whh,
                           const float* __restrict__ bih, const float* __restrict__ bhh,
                           unsigned short* __restrict__ Wx, unsigned short* __restrict__ Wh,
                           float* __restrict__ bias, int Kx) {
  long nx = (long)NG * Kx;
  long nh = (long)NG * NH;
  long total = nx + nh + NG;
  for (long i = (long)blockIdx.x * blockDim.x + threadIdx.x; i < total;
       i += (long)gridDim.x * blockDim.x) {
    if (i < nx) {
      int p = (int)(i / Kx); int k = (int)(i - (long)p * Kx);
      int orig = (p & 3) * NH + (p >> 2);
      Wx[i] = f2bf(Wih[(long)orig * Kx + k]);
    } else if (i < nx + nh) {
      long j = i - nx;
      int p = (int)(j / NH); int k = (int)(j - (long)p * NH);
      int orig = (p & 3) * NH + (p >> 2);
      Wh[j] = f2bf(Whh[(long)orig * NH + k]);
    } else {
      int p = (int)(i - nx - nh);
      int orig = (p & 3) * NH + (p >> 2);
      bias[p] = bih[orig] + bhh[orig];
    }
  }
}

__global__ void prep_emb(const int* __restrict__ tok, const int* __restrict__ lens,
                         const float* __restrict__ enc,
                         unsigned short* __restrict__ embf, unsigned short* __restrict__ embr) {
  int row = blockIdx.x;            // t*BB + b
  int t = row / BB, b = row - (row / BB) * BB;
  int L = lens[b];
  int tf = tok[b * TT + t];
  int ir = (t < L) ? (L - 1 - t) : t;
  int tr_ = tok[b * TT + ir];
  int i = threadIdx.x;             // 0..127 -> 4 floats each
  float4 vf = *(const float4*)(enc + (long)tf * NI + i * 4);
  float4 vr = *(const float4*)(enc + (long)tr_ * NI + i * 4);
  ushort4 of = make_ushort4(f2bf(vf.x), f2bf(vf.y), f2bf(vf.z), f2bf(vf.w));
  ushort4 orr = make_ushort4(f2bf(vr.x), f2bf(vr.y), f2bf(vr.z), f2bf(vr.w));
  *(ushort4*)(embf + (long)row * NI + i * 4) = of;
  *(ushort4*)(embr + (long)row * NI + i * 4) = orr;
}

// ---------------- main persistent kernel ----------------
struct KP {
  const int* lens;
  const unsigned short* emb[2];    // [dir] (T*B, NI) bf16
  const unsigned short* Wx[4];     // [g] (NG, Kx) bf16, permuted rows
  const unsigned short* Wh[4];     // [g] (NG, NH) bf16, permuted rows
  const float* bias[4];            // [g] (NG) f32, permuted rows
  unsigned short* hist[4];         // [g] (T, BB, NH) bf16 write-once h history
  unsigned int* slots;             // 4 groups x 64 per-wg progress slots
  float* out;                      // (T, B, 2048) f32
};

// one-wave global poll of the 64 per-wg slots (sc1 loads, NO cache fence)
static __device__ __forceinline__ void poll64(const unsigned int* slots, unsigned tgt) {
  int lane = threadIdx.x & 63;
  for (;;) {
    unsigned v = __hip_atomic_load(slots + lane, __ATOMIC_RELAXED, __HIP_MEMORY_SCOPE_AGENT);
    if (__all((int)(v >= tgt))) break;
    __builtin_amdgcn_s_sleep(2);
  }
  asm volatile("" ::: "memory");
}

static __device__ __forceinline__ void flag_set(int* f, int v) {
  if ((threadIdx.x & 63) == 0)
    __hip_atomic_store(f, v, __ATOMIC_RELAXED, __HIP_MEMORY_SCOPE_WORKGROUP);
}
static __device__ __forceinline__ void flag_wait(const int* f, int v) {
  while (__hip_atomic_load(f, __ATOMIC_RELAXED, __HIP_MEMORY_SCOPE_WORKGROUP) < v)
    __builtin_amdgcn_s_sleep(1);
  asm volatile("" ::: "memory");
}

// wave owns 64 gate rows x a K-quarter. w[mt*KQ+ks].
template <int KQ>
static __device__ __forceinline__ void loadw_q(bf16x8* w, const unsigned short* Wsrc,
                                               int row0, int kbase, int Kfull,
                                               int ln, int kg) {
#pragma unroll
  for (int mt = 0; mt < 4; ++mt) {
    const unsigned short* p = Wsrc + (long)(row0 + mt * 16 + ln) * Kfull + kbase + kg * 8;
#pragma unroll
    for (int ks = 0; ks < KQ; ++ks) w[mt * KQ + ks] = *(const bf16x8*)(p + ks * 32);
  }
}

// plain cached loads (write-once data => no staleness); depth-2 prefetch
template <int KQ>
static __device__ __forceinline__ void gemm_q(const bf16x8* w, f32x4* acc,
                                              const unsigned short* src, int stride,
                                              int kbase, int ln, int kg) {
  const unsigned short* p0 = src + (long)ln * stride + kbase + kg * 8;
  const long rs = (long)stride * 16;
  bf16x8 bA[4], bB[4];
#pragma unroll
  for (int nt = 0; nt < 4; ++nt) bA[nt] = *(const bf16x8*)(p0 + nt * rs);
  if (KQ > 1) {
#pragma unroll
    for (int nt = 0; nt < 4; ++nt) bB[nt] = *(const bf16x8*)(p0 + nt * rs + 32);
  }
#pragma unroll
  for (int ks = 0; ks < KQ; ++ks) {
#pragma unroll
    for (int mt = 0; mt < 4; ++mt)
#pragma unroll
      for (int nt = 0; nt < 4; ++nt)
        acc[mt * 4 + nt] = __builtin_amdgcn_mfma_f32_16x16x32_bf16(
            w[mt * KQ + ks], (ks & 1) ? bB[nt] : bA[nt], acc[mt * 4 + nt], 0, 0, 0);
    if (ks + 2 < KQ) {
#pragma unroll
      for (int nt = 0; nt < 4; ++nt) {
        bf16x8 v = *(const bf16x8*)(p0 + nt * rs + (ks + 2) * 32);
        if (ks & 1) bB[nt] = v; else bA[nt] = v;
      }
    }
  }
}

// 256 wgs x 512 thr. group g = wg>>6: 0=f0 1=f1 2=r0 3=r1 (dir=g>>1, layer=g&1).
// wg owns 64 permuted gate rows (16 h-cols). wave = part(x|h)*4 + q(K-quarter).
// wave0 polls prev-layer (layer1), wave4 polls own group, wave7 stores h+slot.
__global__ void __launch_bounds__(512, 2) lstm_main(KP P) {
  __shared__ f32x4 red[8 * 16 * 64];          // 128 KB partial-gate sums
  __shared__ unsigned short hrep[64][16];     // 2 KB repack for coalesced h store
  __shared__ int flagO, flagP;
  const int tid = threadIdx.x, lane = tid & 63, wave = tid >> 6;
  const int part = wave >> 2, q = wave & 3;
  const int wg = blockIdx.x, g = wg >> 6, wl = wg & 63;
  const int dir = g >> 1, layer = g & 1;
  const int ln = lane & 15, kg = lane >> 4;
  unsigned int* so = P.slots + g * 64;
  unsigned int* sp = P.slots + (g - 1) * 64;  // valid only when layer==1
  if (tid == 0) { flagO = 0; flagP = 0; }
  __syncthreads();

  bf16x8 w[32];
  const int row0 = wl * 64;
  if (part == 0) {
    if (layer) loadw_q<8>(w, P.Wx[g], row0, q * 256, NH, ln, kg);
    else       loadw_q<4>(w, P.Wx[g], row0, q * 128, NI, ln, kg);
  } else {
    loadw_q<8>(w, P.Wh[g], row0, q * 256, NH, ln, kg);
  }
  unsigned short* hist = P.hist[g];
  const unsigned short* xsrc =
      layer ? (const unsigned short*)P.hist[g - 1] : P.emb[dir];

  // epilogue constants: thread handles units i0=wave*2 and i0+1 at its lane
  const int i0 = wave * 2;
  const int coll = (i0 >> 2) * 4 + kg;        // col within wg's 16
  const int b0 = (i0 & 3) * 16 + ln;
  const int b1 = ((i0 + 1) & 3) * 16 + ln;
  const int gcol = wl * 16 + coll;
  const f32x4 bias_v = *(const f32x4*)(P.bias[g] + gcol * 4);
  const int L0 = P.lens[b0], L1 = P.lens[b1];
  float c0 = 0.f, c1 = 0.f;

  for (int t = 0; t < TT; ++t) {
    f32x4 acc[16];
#pragma unroll
    for (int i = 0; i < 16; ++i) { f32x4 z = {0.f, 0.f, 0.f, 0.f}; acc[i] = z; }

    if (part == 0) {
      if (layer) {
        if (wave == 0) { poll64(sp, (unsigned)(t + 1)); flag_set(&flagP, t + 1); }
        else           flag_wait(&flagP, t + 1);
        gemm_q<8>(w, acc, xsrc + (long)t * BB * NH, NH, q * 256, ln, kg);
      } else {
        gemm_q<4>(w, acc, xsrc + (long)t * BB * NI, NI, q * 128, ln, kg);
      }
    } else if (t > 0) {
      if (wave == 4) { poll64(so, (unsigned)t); flag_set(&flagO, t); }
      else           flag_wait(&flagO, t);
      gemm_q<8>(w, acc, hist + (long)(t - 1) * BB * NH, NH, q * 256, ln, kg);
    }

#pragma unroll
    for (int i = 0; i < 16; ++i) red[(wave * 16 + i) * 64 + lane] = acc[i];
    __syncthreads();

    // epilogue: 2 (batch,col) units per thread; lane-contiguous red reads
#pragma unroll
    for (int u = 0; u < 2; ++u) {
      const int i = i0 + u;
      f32x4 gs = bias_v;
#pragma unroll
      for (int w2 = 0; w2 < 8; ++w2) gs += red[(w2 * 16 + i) * 64 + lane];
      float iv = 1.f / (1.f + __expf(-gs[0]));
      float fv = 1.f / (1.f + __expf(-gs[1]));
      float gv = 1.f - 2.f / (1.f + __expf(2.f * gs[2]));
      float og = 1.f / (1.f + __expf(-gs[3]));
      float cp = u ? c1 : c0;
      float cn = fv * cp + iv * gv;
      if (u) c1 = cn; else c0 = cn;
      float tc = 1.f - 2.f / (1.f + __expf(2.f * cn));
      float hn = og * tc;
      const int Lx = u ? L1 : L0;
      const int bx = u ? b1 : b0;
      float outv = (t < Lx) ? hn : 0.f;   // masked rows feed only masked rows
      hrep[bx][coll] = f2bf(outv);
      if (layer)
        P.out[(long)(t * BB + bx) * 2048 + dir * NH + gcol] = outv;  // plain
    }
    __syncthreads();

    if (wave == 7) {   // coalesced write-once h store + slot release
      unsigned short* hd = hist + (long)t * BB * NH + wl * 16 + (lane & 3) * 4;
      const int rbase = lane >> 2;
#pragma unroll
      for (int rr = 0; rr < 4; ++rr) {
        const int r = rr * 16 + rbase;
        unsigned long long v = *(const unsigned long long*)(&hrep[r][(lane & 3) * 4]);
        __hip_atomic_store((unsigned long long*)(hd + (long)r * NH), v,
                           __ATOMIC_RELAXED, __HIP_MEMORY_SCOPE_AGENT);
      }
      asm volatile("s_waitcnt vmcnt(0)" ::: "memory");
      if (lane == 0)
        __hip_atomic_store(so + wl, (unsigned)(t + 1), __ATOMIC_RELAXED,
                           __HIP_MEMORY_SCOPE_AGENT);
    }
  }
}

extern "C" void kernel_launch(void* const* d_in, const int* in_sizes, int n_in,
                              void* d_out, int out_size, void* d_ws, size_t ws_size,
                              hipStream_t stream) {
  (void)in_sizes; (void)n_in; (void)out_size; (void)ws_size;
  const int* input = (const int*)d_in[0];
  const int* lens  = (const int*)d_in[1];
  const float* enc = (const float*)d_in[2];
  // g = dir*2+layer: 0=f0(3..6) 1=f1(7..10) 2=r0(11..14) 3=r1(15..18)
  const float* Wih[4] = {(const float*)d_in[3],  (const float*)d_in[7],
                         (const float*)d_in[11], (const float*)d_in[15]};
  const float* Whh[4] = {(const float*)d_in[4],  (const float*)d_in[8],
                         (const float*)d_in[12], (const float*)d_in[16]};
  const float* bih[4] = {(const float*)d_in[5],  (const float*)d_in[9],
                         (const float*)d_in[13], (const float*)d_in[17]};
  const float* bhh[4] = {(const float*)d_in[6],  (const float*)d_in[10],
                         (const float*)d_in[14], (const float*)d_in[18]};

  char* ws = (char*)d_ws;
  size_t off = 0;
  auto carve = [&](size_t bytes) -> char* {
    char* p = ws + off;
    off += (bytes + 255) & ~(size_t)255;
    return p;
  };
  unsigned short* emb[2];
  emb[0] = (unsigned short*)carve((size_t)TT * BB * NI * 2);
  emb[1] = (unsigned short*)carve((size_t)TT * BB * NI * 2);
  unsigned short* hist[4];
  for (int g = 0; g < 4; ++g)
    hist[g] = (unsigned short*)carve((size_t)TT * BB * NH * 2);
  unsigned short* Wx[4]; unsigned short* Wh[4]; float* bias[4];
  for (int li = 0; li < 4; ++li) {
    int Kx = (li & 1) ? NH : NI;
    Wx[li]   = (unsigned short*)carve((size_t)NG * Kx * 2);
    Wh[li]   = (unsigned short*)carve((size_t)NG * NH * 2);
    bias[li] = (float*)carve((size_t)NG * 4);
  }
  unsigned int* slots = (unsigned int*)carve(1024);

  hipMemsetAsync(slots, 0, 1024, stream);
  for (int li = 0; li < 4; ++li) {
    int Kx = (li & 1) ? NH : NI;
    prep_layer<<<2048, 256, 0, stream>>>(Wih[li], Whh[li], bih[li], bhh[li],
                                         Wx[li], Wh[li], bias[li], Kx);
  }
  prep_emb<<<TT * BB, 128, 0, stream>>>(input, lens, enc, emb[0], emb[1]);

  KP p;
  p.lens = lens;
  p.emb[0] = emb[0]; p.emb[1] = emb[1];
  for (int li = 0; li < 4; ++li) {
    p.Wx[li] = Wx[li]; p.Wh[li] = Wh[li]; p.bias[li] = bias[li]; p.hist[li] = hist[li];
  }
  p.slots = slots;
  p.out = (float*)d_out;

  void* args[] = {&p};
  hipLaunchCooperativeKernel(lstm_main, dim3(256), dim3(512), args, 0, stream);
}

// Round 4
// 5839.771 us; speedup vs baseline: 8.8496x; 1.1884x over previous
//
#include <hip/hip_runtime.h>

#define TT 512
#define BB 64
#define NI 512
#define NH 1024
#define NG 4096

using bf16x8 = __attribute__((ext_vector_type(8))) __bf16;
using f32x4  = __attribute__((ext_vector_type(4))) float;

static __device__ __forceinline__ unsigned short f2bf(float f) {
  unsigned int u = __float_as_uint(f);
  u += 0x7fffu + ((u >> 16) & 1u);
  return (unsigned short)(u >> 16);
}

// ---------------- prep kernels (proven rounds 0-3) ----------------
// Permute gate rows to p = 4*col + gate (gate order i,f,g,o), convert to bf16,
// fold biases. orig row = gate*NH + col.
__global__ void prep_layer(const float* __restrict__ Wih, const float* __restrict__ Whh,
                           const float* __restrict__ bih, const float* __restrict__ bhh,
                           unsigned short* __restrict__ Wx, unsigned short* __restrict__ Wh,
                           float* __restrict__ bias, int Kx) {
  long nx = (long)NG * Kx;
  long nh = (long)NG * NH;
  long total = nx + nh + NG;
  for (long i = (long)blockIdx.x * blockDim.x + threadIdx.x; i < total;
       i += (long)gridDim.x * blockDim.x) {
    if (i < nx) {
      int p = (int)(i / Kx); int k = (int)(i - (long)p * Kx);
      int orig = (p & 3) * NH + (p >> 2);
      Wx[i] = f2bf(Wih[(long)orig * Kx + k]);
    } else if (i < nx + nh) {
      long j = i - nx;
      int p = (int)(j / NH); int k = (int)(j - (long)p * NH);
      int orig = (p & 3) * NH + (p >> 2);
      Wh[j] = f2bf(Whh[(long)orig * NH + k]);
    } else {
      int p = (int)(i - nx - nh);
      int orig = (p & 3) * NH + (p >> 2);
      bias[p] = bih[orig] + bhh[orig];
    }
  }
}

__global__ void prep_emb(const int* __restrict__ tok, const int* __restrict__ lens,
                         const float* __restrict__ enc,
                         unsigned short* __restrict__ embf, unsigned short* __restrict__ embr) {
  int row = blockIdx.x;            // t*BB + b
  int t = row / BB, b = row - (row / BB) * BB;
  int L = lens[b];
  int tf = tok[b * TT + t];
  int ir = (t < L) ? (L - 1 - t) : t;
  int tr_ = tok[b * TT + ir];
  int i = threadIdx.x;             // 0..127 -> 4 floats each
  float4 vf = *(const float4*)(enc + (long)tf * NI + i * 4);
  float4 vr = *(const float4*)(enc + (long)tr_ * NI + i * 4);
  ushort4 of = make_ushort4(f2bf(vf.x), f2bf(vf.y), f2bf(vf.z), f2bf(vf.w));
  ushort4 orr = make_ushort4(f2bf(vr.x), f2bf(vr.y), f2bf(vr.z), f2bf(vr.w));
  *(ushort4*)(embf + (long)row * NI + i * 4) = of;
  *(ushort4*)(embr + (long)row * NI + i * 4) = orr;
}

// ---------------- main persistent kernel ----------------
struct KP {
  const int* lens;
  const unsigned short* emb[2];    // [dir] (T*B, NI) bf16
  const unsigned short* Wx[4];     // [g] (NG, Kx) bf16, permuted rows
  const unsigned short* Wh[4];     // [g] (NG, NH) bf16, permuted rows
  const float* bias[4];            // [g] (NG) f32, permuted rows
  unsigned short* hist[4];         // [g] (T, BB, NH) bf16 write-once h history
  unsigned int* slots;             // 256 wg slots, 32B padded (slots[wg*8])
  float* out;                      // (T, B, 2048) f32
};

// poll 16 producer slots (one K-quarter's wgs); 32B-padded to spread L3 lines.
// lanes 0-15 map to the 16 slots (lanes 16-63 replicate). No cache fence:
// consumed data is write-once (sc1 to L3) and never previously cached here.
static __device__ __forceinline__ void poll16(const unsigned int* slots, int base,
                                              unsigned tgt) {
  const unsigned int* p = slots + (size_t)(base + ((threadIdx.x & 63) & 15)) * 8;
  for (;;) {
    unsigned v = __hip_atomic_load(p, __ATOMIC_RELAXED, __HIP_MEMORY_SCOPE_AGENT);
    if (__all((int)(v >= tgt))) break;
    __builtin_amdgcn_s_sleep(1);
  }
  asm volatile("" ::: "memory");
}

// wave owns 64 gate rows x a K-quarter. w[mt*KQ+ks].
template <int KQ>
static __device__ __forceinline__ void loadw_q(bf16x8* w, const unsigned short* Wsrc,
                                               int row0, int kbase, int Kfull,
                                               int ln, int kg) {
#pragma unroll
  for (int mt = 0; mt < 4; ++mt) {
    const unsigned short* p = Wsrc + (long)(row0 + mt * 16 + ln) * Kfull + kbase + kg * 8;
#pragma unroll
    for (int ks = 0; ks < KQ; ++ks) w[mt * KQ + ks] = *(const bf16x8*)(p + ks * 32);
  }
}

// plain cached loads (write-once data => no staleness); depth-2 prefetch
template <int KQ>
static __device__ __forceinline__ void gemm_q(const bf16x8* w, f32x4* acc,
                                              const unsigned short* src, int stride,
                                              int kbase, int ln, int kg) {
  const unsigned short* p0 = src + (long)ln * stride + kbase + kg * 8;
  const long rs = (long)stride * 16;
  bf16x8 bA[4], bB[4];
#pragma unroll
  for (int nt = 0; nt < 4; ++nt) bA[nt] = *(const bf16x8*)(p0 + nt * rs);
  if (KQ > 1) {
#pragma unroll
    for (int nt = 0; nt < 4; ++nt) bB[nt] = *(const bf16x8*)(p0 + nt * rs + 32);
  }
#pragma unroll
  for (int ks = 0; ks < KQ; ++ks) {
#pragma unroll
    for (int mt = 0; mt < 4; ++mt)
#pragma unroll
      for (int nt = 0; nt < 4; ++nt)
        acc[mt * 4 + nt] = __builtin_amdgcn_mfma_f32_16x16x32_bf16(
            w[mt * KQ + ks], (ks & 1) ? bB[nt] : bA[nt], acc[mt * 4 + nt], 0, 0, 0);
    if (ks + 2 < KQ) {
#pragma unroll
      for (int nt = 0; nt < 4; ++nt) {
        bf16x8 v = *(const bf16x8*)(p0 + nt * rs + (ks + 2) * 32);
        if (ks & 1) bB[nt] = v; else bA[nt] = v;
      }
    }
  }
}

// 256 wgs x 512 thr. group g = wg>>6: 0=f0 1=f1 2=r0 3=r1 (dir=g>>1, layer=g&1).
// wg owns 64 permuted gate rows (16 h-cols). wave = part(x|h)*4 + q(K-quarter).
// Each dependent wave polls only its 16 producer wgs (subset polling).
__global__ void __launch_bounds__(512, 2) lstm_main(KP P) {
  __shared__ f32x4 red[8 * 16 * 64];          // 128 KB partial-gate sums
  const int tid = threadIdx.x, lane = tid & 63, wave = tid >> 6;
  const int part = wave >> 2, q = wave & 3;
  const int wg = blockIdx.x, g = wg >> 6, wl = wg & 63;
  const int dir = g >> 1, layer = g & 1;
  const int ln = lane & 15, kg = lane >> 4;

  bf16x8 w[32];
  const int row0 = wl * 64;
  if (part == 0) {
    if (layer) loadw_q<8>(w, P.Wx[g], row0, q * 256, NH, ln, kg);
    else {
      loadw_q<4>(w, P.Wx[g], row0, q * 128, NI, ln, kg);
#pragma unroll
      for (int i = 16; i < 32; ++i) w[i] = (bf16x8)0;
    }
  } else {
    loadw_q<8>(w, P.Wh[g], row0, q * 256, NH, ln, kg);
  }
  // pin weights in VGPRs: forbid the compiler from sinking/rematerializing
  // the loads into the tick loop (R3 evidence: VGPR_Count=128 => weights
  // were being re-fetched every tick, thrashing L2).
#pragma unroll
  for (int i = 0; i < 32; ++i)
    asm volatile("" : "+v"(reinterpret_cast<f32x4&>(w[i])));

  unsigned short* hist = P.hist[g];
  const unsigned short* xsrc =
      layer ? (const unsigned short*)P.hist[g - 1] : P.emb[dir];

  // epilogue constants: thread handles units i0=wave*2 and i0+1 at its lane
  const int i0 = wave * 2;
  const int coll = (i0 >> 2) * 4 + kg;        // col within wg's 16
  const int b0 = (i0 & 3) * 16 + ln;
  const int b1 = ((i0 + 1) & 3) * 16 + ln;
  const int gcol = wl * 16 + coll;
  const f32x4 bias_v = *(const f32x4*)(P.bias[g] + gcol * 4);
  const int L0 = P.lens[b0], L1 = P.lens[b1];
  float c0 = 0.f, c1 = 0.f;

  for (int t = 0; t < TT; ++t) {
    f32x4 acc[16];
#pragma unroll
    for (int i = 0; i < 16; ++i) { f32x4 z = {0.f, 0.f, 0.f, 0.f}; acc[i] = z; }

    if (part == 0) {
      if (layer) {
        poll16(P.slots, (g - 1) * 64 + q * 16, (unsigned)(t + 1));
        gemm_q<8>(w, acc, xsrc + (long)t * BB * NH, NH, q * 256, ln, kg);
      } else {
        gemm_q<4>(w, acc, xsrc + (long)t * BB * NI, NI, q * 128, ln, kg);
      }
    } else if (t > 0) {
      poll16(P.slots, g * 64 + q * 16, (unsigned)t);
      gemm_q<8>(w, acc, hist + (long)(t - 1) * BB * NH, NH, q * 256, ln, kg);
    }

#pragma unroll
    for (int i = 0; i < 16; ++i) red[(wave * 16 + i) * 64 + lane] = acc[i];
    __syncthreads();

    // epilogue: 2 (batch,col) units per thread; h stored directly (2B sc1)
    float ov[2];
#pragma unroll
    for (int u = 0; u < 2; ++u) {
      const int i = i0 + u;
      f32x4 gs = bias_v;
#pragma unroll
      for (int w2 = 0; w2 < 8; ++w2) gs += red[(w2 * 16 + i) * 64 + lane];
      float iv = 1.f / (1.f + __expf(-gs[0]));
      float fv = 1.f / (1.f + __expf(-gs[1]));
      float gv = 1.f - 2.f / (1.f + __expf(2.f * gs[2]));
      float og = 1.f / (1.f + __expf(-gs[3]));
      float cp = u ? c1 : c0;
      float cn = fv * cp + iv * gv;
      if (u) c1 = cn; else c0 = cn;
      float tc = 1.f - 2.f / (1.f + __expf(2.f * cn));
      float hn = og * tc;
      const int Lx = u ? L1 : L0;
      const int bx = u ? b1 : b0;
      float outv = (t < Lx) ? hn : 0.f;   // masked rows feed only masked rows
      ov[u] = outv;
      __hip_atomic_store(hist + (long)t * BB * NH + (long)bx * NH + gcol,
                         (unsigned short)f2bf(outv),
                         __ATOMIC_RELAXED, __HIP_MEMORY_SCOPE_AGENT);
    }
    asm volatile("s_waitcnt vmcnt(0)" ::: "memory");   // drain own h stores
    __syncthreads();                                   // all waves drained
    if (tid == 0)
      __hip_atomic_store(P.slots + (size_t)wg * 8, (unsigned)(t + 1),
                         __ATOMIC_RELAXED, __HIP_MEMORY_SCOPE_AGENT);
    if (layer) {   // out stores off the release critical path
      P.out[(long)(t * BB + b0) * 2048 + dir * NH + gcol] = ov[0];
      P.out[(long)(t * BB + b1) * 2048 + dir * NH + gcol] = ov[1];
    }
  }
}

extern "C" void kernel_launch(void* const* d_in, const int* in_sizes, int n_in,
                              void* d_out, int out_size, void* d_ws, size_t ws_size,
                              hipStream_t stream) {
  (void)in_sizes; (void)n_in; (void)out_size; (void)ws_size;
  const int* input = (const int*)d_in[0];
  const int* lens  = (const int*)d_in[1];
  const float* enc = (const float*)d_in[2];
  // g = dir*2+layer: 0=f0(3..6) 1=f1(7..10) 2=r0(11..14) 3=r1(15..18)
  const float* Wih[4] = {(const float*)d_in[3],  (const float*)d_in[7],
                         (const float*)d_in[11], (const float*)d_in[15]};
  const float* Whh[4] = {(const float*)d_in[4],  (const float*)d_in[8],
                         (const float*)d_in[12], (const float*)d_in[16]};
  const float* bih[4] = {(const float*)d_in[5],  (const float*)d_in[9],
                         (const float*)d_in[13], (const float*)d_in[17]};
  const float* bhh[4] = {(const float*)d_in[6],  (const float*)d_in[10],
                         (const float*)d_in[14], (const float*)d_in[18]};

  char* ws = (char*)d_ws;
  size_t off = 0;
  auto carve = [&](size_t bytes) -> char* {
    char* p = ws + off;
    off += (bytes + 255) & ~(size_t)255;
    return p;
  };
  unsigned short* emb[2];
  emb[0] = (unsigned short*)carve((size_t)TT * BB * NI * 2);
  emb[1] = (unsigned short*)carve((size_t)TT * BB * NI * 2);
  unsigned short* hist[4];
  for (int g = 0; g < 4; ++g)
    hist[g] = (unsigned short*)carve((size_t)TT * BB * NH * 2);
  unsigned short* Wx[4]; unsigned short* Wh[4]; float* bias[4];
  for (int li = 0; li < 4; ++li) {
    int Kx = (li & 1) ? NH : NI;
    Wx[li]   = (unsigned short*)carve((size_t)NG * Kx * 2);
    Wh[li]   = (unsigned short*)carve((size_t)NG * NH * 2);
    bias[li] = (float*)carve((size_t)NG * 4);
  }
  unsigned int* slots = (unsigned int*)carve(256 * 32);

  hipMemsetAsync(slots, 0, 256 * 32, stream);
  for (int li = 0; li < 4; ++li) {
    int Kx = (li & 1) ? NH : NI;
    prep_layer<<<2048, 256, 0, stream>>>(Wih[li], Whh[li], bih[li], bhh[li],
                                         Wx[li], Wh[li], bias[li], Kx);
  }
  prep_emb<<<TT * BB, 128, 0, stream>>>(input, lens, enc, emb[0], emb[1]);

  KP p;
  p.lens = lens;
  p.emb[0] = emb[0]; p.emb[1] = emb[1];
  for (int li = 0; li < 4; ++li) {
    p.Wx[li] = Wx[li]; p.Wh[li] = Wh[li]; p.bias[li] = bias[li]; p.hist[li] = hist[li];
  }
  p.slots = slots;
  p.out = (float*)d_out;

  void* args[] = {&p};
  hipLaunchCooperativeKernel(lstm_main, dim3(256), dim3(512), args, 0, stream);
}